// Round 5
// baseline (127.899 us; speedup 1.0000x reference)
//
#include <hip/hip_runtime.h>

#define BS 4096
#define LL 512
#define TS 16
#define NT (LL / TS)
#define START_TAG 1
#define END_TAG 2
#define BIASF 4.75f
#define L2E 1.44269504f

typedef float f32x4 __attribute__((ext_vector_type(4)));
typedef short s16x4 __attribute__((ext_vector_type(4)));
union BF4 { unsigned u[2]; s16x4 s; };

__device__ __forceinline__ unsigned cvt_pk_bf16(float lo, float hi) {
    unsigned r;
    asm("v_cvt_pk_bf16_f32 %0, %1, %2" : "=v"(r) : "v"(lo), "v"(hi));
    return r;
}
__device__ __forceinline__ float blo(unsigned u) { return __uint_as_float(u << 16); }
__device__ __forceinline__ float bhi(unsigned u) { return __uint_as_float(u & 0xFFFF0000u); }

// async global->LDS, 16B per lane; LDS dest = uniform base + lane*16 (HW rule)
__device__ __forceinline__ void gll16(const void* g, void* l) {
    __builtin_amdgcn_global_load_lds(
        (const __attribute__((address_space(1))) void*)g,
        (__attribute__((address_space(3))) void*)l, 16, 0, 0);
}

// Stage one 16-step tile for 16 batches: em 16KB (16 instrs), mk 1KB (1), tags (TGI instrs).
template<int TGI>
__device__ __forceinline__ void stage_tile(
    const float* __restrict__ em, const float* __restrict__ mk,
    const int* __restrict__ tg, float* s_em, float* s_mk, int* s_tg,
    int ti, int slot, long b, int q)
{
    const long eb = (b << 13) + ((long)ti << 8) + (q << 2);
#pragma unroll
    for (int s = 0; s < TS; ++s)
        gll16(em + eb + (s << 4), s_em + slot * 4096 + s * 256);
    gll16(mk + (b << 9) + (ti << 4) + (q << 2), s_mk + slot * 256);
    if constexpr (TGI == 2) {      // int64 tags: 2KB = 2 instrs
        const unsigned long long* t64 = (const unsigned long long*)tg;
        gll16(t64 + (b << 9) + (ti << 4) + (q << 1),     s_tg + slot * 512);
        gll16(t64 + (b << 9) + (ti << 4) + 8 + (q << 1), s_tg + slot * 512 + 256);
    } else {                       // int32 tags: 1KB = 1 instr
        gll16(tg + (b << 9) + (ti << 4) + (q << 2), s_tg + slot * 512);
    }
}

// One wave = 16 batches, exp-space vector recursion (batch = MFMA columns):
//   D = E^T * B;  B'[r][c] = D[r][c] * e^{em[b_c][t][r]} * 2^-BIASF  (mask select)
template<int TGI>
__device__ void run(const float* __restrict__ em, const int* __restrict__ tg,
                    const float* __restrict__ mk, float* __restrict__ out,
                    const float* s_tr, float* s_em, float* s_mk, int* s_tg)
{
    const int lane = threadIdx.x;
    const int j = lane & 15, q = lane >> 4;
    const long b = (long)blockIdx.x * 16 + j;

    // A = E^T: lane(j,q) holds A[j][4q+i] = exp(tr[4q+i][j])  (exp(-1000)->0)
    float Te[4]; BF4 A;
    {
        float Ef[4];
#pragma unroll
        for (int i = 0; i < 4; ++i) {
            Ef[i] = expf(s_tr[(q * 4 + i) * 16 + j]);
            Te[i] = s_tr[(q * 4 + i) * 16 + END_TAG];
        }
        A.u[0] = cvt_pk_bf16(Ef[0], Ef[1]);
        A.u[1] = cvt_pk_bf16(Ef[2], Ef[3]);
    }

    unsigned p01 = 0x3F803F80u, p23 = 0x3F803F80u;   // alpha = exp(0) = 1
    float e2f = 0.f, cnt = 0.f, sc = 0.f;
    int tprev = START_TAG;

    stage_tile<TGI>(em, mk, tg, s_em, s_mk, s_tg, 0, 0, b, q);
    stage_tile<TGI>(em, mk, tg, s_em, s_mk, s_tg, 1, 1, b, q);
    stage_tile<TGI>(em, mk, tg, s_em, s_mk, s_tg, 2, 2, b, q);

    int slot = 0;
    for (int i = 0; i < NT; ++i) {
        // tile i complete when <= 2 tiles (2*(17+TGI) loads) remain in flight
        if constexpr (TGI == 2) asm volatile("s_waitcnt vmcnt(36)" ::: "memory");
        else                    asm volatile("s_waitcnt vmcnt(34)" ::: "memory");
        __builtin_amdgcn_sched_barrier(0);

        const float* eb = s_em + slot * 4096;
        const float* mb = s_mk + slot * 256;
        const int*   tb = s_tg + slot * 512;
#pragma unroll
        for (int s = 0; s < TS; ++s) {
            const f32x4 ev = *(const f32x4*)(eb + s * 256 + lane * 4);
            const float um = mb[((s >> 2) << 6) + (j << 2) + (s & 3)];
            int tcur;
            if constexpr (TGI == 2)
                tcur = tb[((s >> 3) << 8) + (((s >> 1) & 3) << 6) + (j << 2) + ((s & 1) << 1)];
            else
                tcur = tb[((s >> 2) << 6) + (j << 2) + (s & 3)];

            const float e0 = exp2f(fmaf(ev.x, L2E, -BIASF));
            const float e1 = exp2f(fmaf(ev.y, L2E, -BIASF));
            const float e2 = exp2f(fmaf(ev.z, L2E, -BIASF));
            const float e3 = exp2f(fmaf(ev.w, L2E, -BIASF));
            BF4 Bp; Bp.u[0] = p01; Bp.u[1] = p23;
            f32x4 z = {0.f, 0.f, 0.f, 0.f};
            f32x4 d = __builtin_amdgcn_mfma_f32_16x16x16bf16_1k(A.s, Bp.s, z, 0, 0, 0);
            const unsigned n01 = cvt_pk_bf16(d[0] * e0, d[1] * e1);
            const unsigned n23 = cvt_pk_bf16(d[2] * e2, d[3] * e3);
            const bool up = um > 0.f;
            p01 = up ? n01 : p01;
            p23 = up ? n23 : p23;
            cnt += um;

            const int t = i * TS + s;
            const float scm = (t == 0) ? 1.f : um;
            const int   tpv = (t == 0) ? START_TAG : tprev;
            const float tv  = s_tr[tpv * 16 + tcur];
            if ((tcur >> 2) == q) {                    // fused path-score gather
                const float es = (tcur & 2) ? ((tcur & 1) ? ev.w : ev.z)
                                            : ((tcur & 1) ? ev.y : ev.x);
                sc = fmaf(es + tv, scm, sc);
            }
            tprev = tcur;
        }

        // exact power-of-2 per-column renorm (per 16 steps)
        {
            const float v0 = blo(p01), v1 = bhi(p01), v2 = blo(p23), v3 = bhi(p23);
            float mm = fmaxf(fmaxf(v0, v1), fmaxf(v2, v3));
            mm = fmaxf(mm, __shfl_xor(mm, 16));
            mm = fmaxf(mm, __shfl_xor(mm, 32));
            if (mm > 0.f) {
                const int ex = (int)((__float_as_uint(mm) >> 23) & 0xFFu) - 127;
                const float sre = __uint_as_float((unsigned)(127 - ex) << 23);
                e2f += (float)ex;
                p01 = cvt_pk_bf16(v0 * sre, v1 * sre);
                p23 = cvt_pk_bf16(v2 * sre, v3 * sre);
            }
        }

        // all ds_reads done before this slot's LDS is overwritten by new stage
        asm volatile("s_waitcnt lgkmcnt(0)" ::: "memory");
        __builtin_amdgcn_sched_barrier(0);
        const int nti = (i + 3 < NT) ? (i + 3) : (NT - 1);  // dummies keep vmcnt uniform
        stage_tile<TGI>(em, mk, tg, s_em, s_mk, s_tg, nti, slot, b, q);
        slot = (slot == 2) ? 0 : slot + 1;
    }

    // ---- epilogue (identical math to round 4) ----
    sc += __shfl_xor(sc, 16);
    sc += __shfl_xor(sc, 32);

    const float v0 = blo(p01), v1 = bhi(p01), v2 = blo(p23), v3 = bhi(p23);
    const float b2 = e2f + BIASF * cnt;
    const float y0 = log2f(v0) + b2 + Te[0] * L2E;
    const float y1 = log2f(v1) + b2 + Te[1] * L2E;
    const float y2 = log2f(v2) + b2 + Te[2] * L2E;
    const float y3 = log2f(v3) + b2 + Te[3] * L2E;
    float m2 = fmaxf(fmaxf(y0, y1), fmaxf(y2, y3));
    m2 = fmaxf(m2, __shfl_xor(m2, 16));
    m2 = fmaxf(m2, __shfl_xor(m2, 32));
    m2 = fmaxf(m2, -1e30f);
    float ee = exp2f(y0 - m2) + exp2f(y1 - m2) + exp2f(y2 - m2) + exp2f(y3 - m2);
    ee += __shfl_xor(ee, 16);
    ee += __shfl_xor(ee, 32);
    const float dp = (m2 + log2f(ee)) * 0.69314718055994531f;

    float res = 0.f;
    if (q == 0) {
        const int li = (int)cnt - 1;
        const int lt = tg[(b << 9) * TGI + li * TGI];   // low word of i64 ok (LE)
        res = dp - (sc + s_tr[lt * 16 + END_TAG]);
    }
    res += __shfl_xor(res, 1);
    res += __shfl_xor(res, 2);
    res += __shfl_xor(res, 4);
    res += __shfl_xor(res, 8);
    if (lane == 0) atomicAdd(out, res);
}

__global__ __launch_bounds__(64, 1) void crf_vec16s(
    const float* __restrict__ em, const int* __restrict__ tg,
    const float* __restrict__ mk, const float* __restrict__ tr,
    float* __restrict__ out)
{
    __shared__ float s_tr[256];
    __shared__ float s_em[3 * 4096];
    __shared__ float s_mk[3 * 256];
    __shared__ int   s_tg[3 * 512];

    const int lane = threadIdx.x;
    *(f32x4*)(s_tr + lane * 4) = *(const f32x4*)(tr + lane * 4);
    __syncthreads();

    // tags dtype detect: 16 u64 words all < 16  =>  int64 layout
    int is64 = 1;
    {
        const unsigned long long* t64 = (const unsigned long long*)tg;
#pragma unroll
        for (int i = 0; i < 16; ++i) is64 &= (t64[i] < 16ull) ? 1 : 0;
    }

    if (is64) run<2>(em, tg, mk, out, s_tr, s_em, s_mk, s_tg);
    else      run<1>(em, tg, mk, out, s_tr, s_em, s_mk, s_tg);
}

extern "C" void kernel_launch(void* const* d_in, const int* in_sizes, int n_in,
                              void* d_out, int out_size, void* d_ws, size_t ws_size,
                              hipStream_t stream) {
    const float* em = (const float*)d_in[0];
    const int*   tg = (const int*)d_in[1];
    const float* mk = (const float*)d_in[2];
    const float* tr = (const float*)d_in[3];
    float* out = (float*)d_out;

    hipMemsetAsync(out, 0, sizeof(float), stream);
    crf_vec16s<<<BS / 16, 64, 0, stream>>>(em, tg, mk, tr, out);
}